// Round 1
// baseline (339.045 us; speedup 1.0000x reference)
//
#include <hip/hip_runtime.h>
#include <hip/hip_bf16.h>

#define T_DIM 2048
#define S_DIM 2048
#define B_DIM 4
#define H_DIM 8
#define HID   256
#define NTOK  (T_DIM*B_DIM)
#define LOG2E 1.44269504088896340736f

typedef __attribute__((ext_vector_type(8))) short bf16x8;
typedef __attribute__((ext_vector_type(4))) float f32x4;

static __device__ __forceinline__ short f2bf(float f){
    unsigned u = __builtin_bit_cast(unsigned, f);
    u = (u + 0x7FFFu + ((u >> 16) & 1u)) >> 16;   // RNE, inputs are well-behaved
    return (short)u;
}

// ---------------- weight prep: fp32 -> bf16, transposed to K-major ----------------
__global__ void prep_weights(const float* Wq1, const float* Wk1, const float* Wv1,
                             const float* Wq2, const float* Wk2, const float* Wv2,
                             const float* Wo,
                             short* W1t, short* W2t, short* Wot)
{
    int gid = blockIdx.x * blockDim.x + threadIdx.x;
    int stride = gridDim.x * blockDim.x;
    // W1t[p][j][i] = W1_p[i][j]   (j<256 hid, i<64 in)
    for (int idx = gid; idx < 3 * HID * 64; idx += stride){
        int p = idx / (HID * 64); int o = idx % (HID * 64);
        int j = o >> 6, i = o & 63;
        const float* W = (p == 0) ? Wq1 : (p == 1) ? Wk1 : Wv1;
        W1t[idx] = f2bf(W[i * HID + j]);
    }
    // W2t[p][n][k] = W2_p[k][n]   (n<512, k<256)
    for (int idx = gid; idx < 3 * 512 * HID; idx += stride){
        int p = idx / (512 * HID); int o = idx % (512 * HID);
        int n = o >> 8, k = o & 255;
        const float* W = (p == 0) ? Wq2 : (p == 1) ? Wk2 : Wv2;
        W2t[idx] = f2bf(W[k * 512 + n]);
    }
    // Wot[n][k] = Wo[k][n]   (n<64, k<512)
    for (int idx = gid; idx < 64 * 512; idx += stride){
        int n = idx >> 9, k = idx & 511;
        Wot[idx] = f2bf(Wo[k * 64 + n]);
    }
}

// ---------------- per-token 2-layer MLP projections (q/k/v) ----------------
// grid (NTOK/64, 3), 256 threads. Wave w owns tokens tok0+w*16 .. +15.
__global__ __launch_bounds__(256) void proj_kernel(
    const float* query, const float* key, const float* value,
    const short* W1t_all, const short* W2t_all,
    const float* bq1, const float* bk1, const float* bv1,
    const float* bq2, const float* bk2, const float* bv2,
    short* q_bh, short* k_bh, short* v_bh)
{
    int p = blockIdx.y;
    const float* X  = (p == 0) ? query : (p == 1) ? key : value;
    const short* W1 = W1t_all + p * HID * 64;
    const short* W2 = W2t_all + p * 512 * HID;
    const float* b1 = (p == 0) ? bq1 : (p == 1) ? bk1 : bv1;
    const float* b2 = (p == 0) ? bq2 : (p == 1) ? bk2 : bv2;
    short* OUT = (p == 0) ? q_bh : (p == 1) ? k_bh : v_bh;
    float oscale = (p == 0) ? 0.125f : 1.0f;   // d_q^-0.5 folded into q

    __shared__ short Hs[64 * HID];   // [64 tok][256] bf16, XOR-swizzled rows

    int tid = threadIdx.x;
    int wave = tid >> 6, lane = tid & 63;
    int lg = lane >> 4, lr = lane & 15;
    int tok0 = blockIdx.x * 64;

    // layer-1 A-frags: A[row=lr][k=lg*8+j], converted from fp32
    const float* xrow = X + (tok0 + wave * 16 + lr) * 64;
    bf16x8 a0, a1;
    #pragma unroll
    for (int j = 0; j < 8; j++){
        a0[j] = f2bf(xrow[lg * 8 + j]);
        a1[j] = f2bf(xrow[32 + lg * 8 + j]);
    }

    f32x4 accH[16];
    #pragma unroll
    for (int nb = 0; nb < 16; nb++) accH[nb] = 0.f;
    #pragma unroll
    for (int nb = 0; nb < 16; nb++){
        const short* w = W1 + (nb * 16 + lr) * 64;   // W1t row n (K-major)
        bf16x8 wb0 = *(const bf16x8*)(w + lg * 8);
        bf16x8 wb1 = *(const bf16x8*)(w + 32 + lg * 8);
        accH[nb] = __builtin_amdgcn_mfma_f32_16x16x32_bf16(a0, wb0, accH[nb], 0, 0, 0);
        accH[nb] = __builtin_amdgcn_mfma_f32_16x16x32_bf16(a1, wb1, accH[nb], 0, 0, 0);
    }
    // bias + ReLU -> Hs (swizzled); rows are per-wave private, DS is in-order -> no barrier
    #pragma unroll
    for (int nb = 0; nb < 16; nb++){
        int col = nb * 16 + lr;
        float bias = b1[col];
        #pragma unroll
        for (int r = 0; r < 4; r++){
            int row = wave * 16 + lg * 4 + r;
            float hv = accH[nb][r] + bias;
            hv = hv > 0.f ? hv : 0.f;
            Hs[row * HID + (col ^ ((row & 7) << 3))] = f2bf(hv);
        }
    }
    // layer-2 A-frags from Hs
    int hrow = wave * 16 + lr;
    bf16x8 ha[8];
    #pragma unroll
    for (int ks = 0; ks < 8; ks++){
        int col = ks * 32 + lg * 8;
        ha[ks] = *(const bf16x8*)(Hs + hrow * HID + (col ^ ((hrow & 7) << 3)));
    }
    #pragma unroll 1
    for (int nt = 0; nt < 8; nt++){     // 8 n-tiles of 64 outputs = one head each
        f32x4 acc[4];
        #pragma unroll
        for (int nb = 0; nb < 4; nb++) acc[nb] = 0.f;
        #pragma unroll
        for (int ks = 0; ks < 8; ks++){
            #pragma unroll
            for (int nb = 0; nb < 4; nb++){
                int n = nt * 64 + nb * 16 + lr;
                bf16x8 wb = *(const bf16x8*)(W2 + n * HID + ks * 32 + lg * 8);
                acc[nb] = __builtin_amdgcn_mfma_f32_16x16x32_bf16(ha[ks], wb, acc[nb], 0, 0, 0);
            }
        }
        #pragma unroll
        for (int nb = 0; nb < 4; nb++){
            int d = nb * 16 + lr;
            float bias = b2[nt * 64 + d];
            #pragma unroll
            for (int r = 0; r < 4; r++){
                int token = tok0 + wave * 16 + lg * 4 + r;
                int t = token >> 2, bb = token & 3;
                float v = (acc[nb][r] + bias) * oscale;
                OUT[(((bb * H_DIM + nt) * T_DIM) + t) * 64 + d] = f2bf(v);
            }
        }
    }
}

// ---------------- flash attention: one (q-tile, b*h) per block ----------------
__global__ __launch_bounds__(256) void attn_kernel(
    const short* q_bh, const short* k_bh, const short* v_bh,
    const float* mask, short* attn_buf)
{
    int bx = blockIdx.x;          // q tile (64 rows)
    int by = blockIdx.y;          // b*8 + h
    int b = by >> 3, h = by & 7;
    int tid = threadIdx.x, wave = tid >> 6, lane = tid & 63;
    int lg = lane >> 4, lr = lane & 15;

    const short* Qb = q_bh + by * (T_DIM * 64);
    const short* Kb = k_bh + by * (S_DIM * 64);
    const short* Vb = v_bh + by * (S_DIM * 64);

    __shared__ short Ks [64 * 64];     // [s][d], swizzled
    __shared__ short Vts[64 * 64];     // [d][s], swizzled (transposed at staging)
    __shared__ short Ps [4][16 * 64];  // per-wave P scratch, swizzled

    // Q fragments held in registers for the whole block
    const short* qrow = Qb + (bx * 64 + wave * 16 + lr) * 64;
    bf16x8 qa0 = *(const bf16x8*)(qrow + lg * 8);
    bf16x8 qa1 = *(const bf16x8*)(qrow + 32 + lg * 8);

    float m[4], lsum[4];
    f32x4 oacc[4];
    #pragma unroll
    for (int r = 0; r < 4; r++){ m[r] = -1e30f; lsum[r] = 0.f; }
    #pragma unroll
    for (int nb = 0; nb < 4; nb++) oacc[nb] = 0.f;

    int mbase[4];
    #pragma unroll
    for (int r = 0; r < 4; r++){
        int t = bx * 64 + wave * 16 + lg * 4 + r;
        mbase[r] = (b * T_DIM + t) * S_DIM;
    }

    int sK = tid >> 2, d0 = (tid & 3) * 16;        // K staging mapping
    int vd = tid & 63, vsb = (tid >> 6) * 16;      // V staging mapping

    for (int st = 0; st < S_DIM / 64; st++){
        int s0 = st * 64;
        { // stage K tile [64][64]
            const short* src = Kb + (s0 + sK) * 64 + d0;
            bf16x8 k0 = *(const bf16x8*)(src);
            bf16x8 k1 = *(const bf16x8*)(src + 8);
            *(bf16x8*)(Ks + sK * 64 + ( d0      ^ ((sK & 7) << 3))) = k0;
            *(bf16x8*)(Ks + sK * 64 + ((d0 + 8) ^ ((sK & 7) << 3))) = k1;
        }
        { // stage V transposed: Vts[d][s]
            short vreg[16];
            #pragma unroll
            for (int i = 0; i < 16; i++) vreg[i] = Vb[(s0 + vsb + i) * 64 + vd];
            #pragma unroll
            for (int c = 0; c < 2; c++){
                bf16x8 w;
                #pragma unroll
                for (int j = 0; j < 8; j++) w[j] = vreg[c * 8 + j];
                *(bf16x8*)(Vts + vd * 64 + ((vsb + c * 8) ^ ((vd & 7) << 3))) = w;
            }
        }
        __syncthreads();

        // QK^T: D[q-row][s-col]
        f32x4 sc[4];
        #pragma unroll
        for (int nb = 0; nb < 4; nb++){
            int n = nb * 16 + lr;
            bf16x8 kb0 = *(const bf16x8*)(Ks + n * 64 + (( lg * 8)      ^ ((n & 7) << 3)));
            bf16x8 kb1 = *(const bf16x8*)(Ks + n * 64 + ((32 + lg * 8)  ^ ((n & 7) << 3)));
            f32x4 z = 0.f;
            z = __builtin_amdgcn_mfma_f32_16x16x32_bf16(qa0, kb0, z, 0, 0, 0);
            sc[nb] = __builtin_amdgcn_mfma_f32_16x16x32_bf16(qa1, kb1, z, 0, 0, 0);
        }
        // + mask, online softmax (row lives across 16 lanes x 4 nb)
        float pv[4][4], rmax[4];
        #pragma unroll
        for (int r = 0; r < 4; r++) rmax[r] = -1e30f;
        #pragma unroll
        for (int nb = 0; nb < 4; nb++){
            int s = s0 + nb * 16 + lr;
            #pragma unroll
            for (int r = 0; r < 4; r++){
                float sv = sc[nb][r] + mask[mbase[r] + s];
                pv[nb][r] = sv;
                rmax[r] = fmaxf(rmax[r], sv);
            }
        }
        #pragma unroll
        for (int r = 0; r < 4; r++){
            float v = rmax[r];
            v = fmaxf(v, __shfl_xor(v, 1, 64));
            v = fmaxf(v, __shfl_xor(v, 2, 64));
            v = fmaxf(v, __shfl_xor(v, 4, 64));
            v = fmaxf(v, __shfl_xor(v, 8, 64));
            float mnew = fmaxf(m[r], v);
            float scale = exp2f((m[r] - mnew) * LOG2E);
            float rsum = 0.f;
            #pragma unroll
            for (int nb = 0; nb < 4; nb++){
                float e = exp2f((pv[nb][r] - mnew) * LOG2E);
                pv[nb][r] = e;
                rsum += e;
            }
            rsum += __shfl_xor(rsum, 1, 64);
            rsum += __shfl_xor(rsum, 2, 64);
            rsum += __shfl_xor(rsum, 4, 64);
            rsum += __shfl_xor(rsum, 8, 64);
            lsum[r] = lsum[r] * scale + rsum;
            m[r] = mnew;
            #pragma unroll
            for (int nb = 0; nb < 4; nb++) oacc[nb][r] *= scale;
        }
        // P -> per-wave LDS (re-fragment D-layout -> A-layout)
        #pragma unroll
        for (int nb = 0; nb < 4; nb++){
            int col = nb * 16 + lr;
            #pragma unroll
            for (int r = 0; r < 4; r++){
                int row = lg * 4 + r;
                Ps[wave][row * 64 + (col ^ ((row & 7) << 3))] = f2bf(pv[nb][r]);
            }
        }
        bf16x8 pa0 = *(const bf16x8*)(&Ps[wave][lr * 64 + (( lg * 8)     ^ ((lr & 7) << 3))]);
        bf16x8 pa1 = *(const bf16x8*)(&Ps[wave][lr * 64 + ((32 + lg * 8) ^ ((lr & 7) << 3))]);
        // PV: D[q-row][d]
        #pragma unroll
        for (int nb = 0; nb < 4; nb++){
            int d = nb * 16 + lr;
            bf16x8 vb0 = *(const bf16x8*)(Vts + d * 64 + (( lg * 8)     ^ ((d & 7) << 3)));
            bf16x8 vb1 = *(const bf16x8*)(Vts + d * 64 + ((32 + lg * 8) ^ ((d & 7) << 3)));
            oacc[nb] = __builtin_amdgcn_mfma_f32_16x16x32_bf16(pa0, vb0, oacc[nb], 0, 0, 0);
            oacc[nb] = __builtin_amdgcn_mfma_f32_16x16x32_bf16(pa1, vb1, oacc[nb], 0, 0, 0);
        }
        __syncthreads();
    }
    // epilogue -> attn_buf [token][h*64+d] bf16
    #pragma unroll
    for (int nb = 0; nb < 4; nb++){
        int d = nb * 16 + lr;
        #pragma unroll
        for (int r = 0; r < 4; r++){
            int t = bx * 64 + wave * 16 + lg * 4 + r;
            int token = t * B_DIM + b;
            float v = oacc[nb][r] / lsum[r];
            attn_buf[token * 512 + h * 64 + d] = f2bf(v);
        }
    }
}

// ---------------- output projection: [8192,512] @ Wo[512,64] + bo ----------------
__global__ __launch_bounds__(256) void oproj_kernel(const short* attn_buf, const short* Wot,
                                                    const float* bo, float* out)
{
    int tid = threadIdx.x, wave = tid >> 6, lane = tid & 63;
    int lg = lane >> 4, lr = lane & 15;
    int tok0 = blockIdx.x * 64;
    const short* arow = attn_buf + (tok0 + wave * 16 + lr) * 512;
    f32x4 acc[4];
    #pragma unroll
    for (int nb = 0; nb < 4; nb++) acc[nb] = 0.f;
    #pragma unroll 4
    for (int ks = 0; ks < 16; ks++){
        bf16x8 a = *(const bf16x8*)(arow + ks * 32 + lg * 8);
        #pragma unroll
        for (int nb = 0; nb < 4; nb++){
            bf16x8 wb = *(const bf16x8*)(Wot + (nb * 16 + lr) * 512 + ks * 32 + lg * 8);
            acc[nb] = __builtin_amdgcn_mfma_f32_16x16x32_bf16(a, wb, acc[nb], 0, 0, 0);
        }
    }
    #pragma unroll
    for (int nb = 0; nb < 4; nb++){
        int d = nb * 16 + lr;
        float bias = bo[d];
        #pragma unroll
        for (int r = 0; r < 4; r++){
            int token = tok0 + wave * 16 + lg * 4 + r;
            out[token * 64 + d] = acc[nb][r] + bias;
        }
    }
}

extern "C" void kernel_launch(void* const* d_in, const int* in_sizes, int n_in,
                              void* d_out, int out_size, void* d_ws, size_t ws_size,
                              hipStream_t stream)
{
    const float* query = (const float*)d_in[0];
    const float* key   = (const float*)d_in[1];
    const float* value = (const float*)d_in[2];
    const float* mask  = (const float*)d_in[3];
    const float* Wq1 = (const float*)d_in[4];  const float* bq1 = (const float*)d_in[5];
    const float* Wq2 = (const float*)d_in[6];  const float* bq2 = (const float*)d_in[7];
    const float* Wk1 = (const float*)d_in[8];  const float* bk1 = (const float*)d_in[9];
    const float* Wk2 = (const float*)d_in[10]; const float* bk2 = (const float*)d_in[11];
    const float* Wv1 = (const float*)d_in[12]; const float* bv1 = (const float*)d_in[13];
    const float* Wv2 = (const float*)d_in[14]; const float* bv2 = (const float*)d_in[15];
    const float* Wo  = (const float*)d_in[16]; const float* bo  = (const float*)d_in[17];

    short* ws      = (short*)d_ws;
    short* q_bh    = ws;                          // [4][8][2048][64] bf16 = 8 MB
    short* k_bh    = q_bh    + 4 * 1024 * 1024;   // 8 MB
    short* v_bh    = k_bh    + 4 * 1024 * 1024;   // 8 MB
    short* attn_b  = v_bh    + 4 * 1024 * 1024;   // [8192][512] bf16 = 8 MB
    short* W1t     = attn_b  + 4 * 1024 * 1024;   // 3*16384
    short* W2t     = W1t     + 3 * HID * 64;      // 3*131072
    short* Wot     = W2t     + 3 * 512 * HID;     // 32768

    prep_weights<<<64, 256, 0, stream>>>(Wq1, Wk1, Wv1, Wq2, Wk2, Wv2, Wo, W1t, W2t, Wot);
    proj_kernel<<<dim3(NTOK / 64, 3), 256, 0, stream>>>(query, key, value, W1t, W2t,
                                                        bq1, bk1, bv1, bq2, bk2, bv2,
                                                        q_bh, k_bh, v_bh);
    attn_kernel<<<dim3(T_DIM / 64, B_DIM * H_DIM), 256, 0, stream>>>(q_bh, k_bh, v_bh, mask, attn_b);
    oproj_kernel<<<NTOK / 64, 256, 0, stream>>>(attn_b, Wot, bo, (float*)d_out);
}